// Round 16
// baseline (279.144 us; speedup 1.0000x reference)
//
#include <hip/hip_runtime.h>
#include <hip/hip_bf16.h>

typedef unsigned short u16;
typedef unsigned int u32;
typedef __bf16 bf16x8 __attribute__((ext_vector_type(8)));
typedef float f32x4 __attribute__((ext_vector_type(4)));

#define DIM 128
#define LROW 40   // padded LDS row stride in u16 (80 B → all 8 b128 start windows)

__device__ __forceinline__ u16 f2bf_rne(float x) {
  u32 u = __float_as_uint(x);
  return (u16)((u + 0x7fffu + ((u >> 16) & 1u)) >> 16);
}
__device__ __forceinline__ u32 packbf2(float x, float y) {
  return (u32)f2bf_rne(x) | ((u32)f2bf_rne(y) << 16);
}
__device__ __forceinline__ float lrelu(float x) { return x > 0.f ? x : 0.01f * x; }
__device__ __forceinline__ int iclamp(int v, int hi) { return v < 0 ? 0 : (v >= hi ? hi - 1 : v); }
__device__ __forceinline__ float sane(float x) { return (x == x) ? x : 0.f; }

__device__ __forceinline__ float wred_max(float v) {
  #pragma unroll
  for (int o = 32; o > 0; o >>= 1) v = fmaxf(v, __shfl_xor(v, o, 64));
  return v;
}
__device__ __forceinline__ float wred_sum(float v) {
  #pragma unroll
  for (int o = 32; o > 0; o >>= 1) v += __shfl_xor(v, o, 64);
  return v;
}

// ---------------- CSR build ----------------
__global__ void hist_k(const int* __restrict__ dst, int* __restrict__ cnt, int E, int N) {
  int e = blockIdx.x * blockDim.x + threadIdx.x;
  if (e < E) {
    int d = dst[e];
    if (d >= 0 && d < N) atomicAdd(&cnt[d], 1);
  }
}

__global__ __launch_bounds__(1024) void scan_k(const int* __restrict__ cnt,
                                               int* __restrict__ offs, int N) {
  __shared__ int sums[1024];
  int t = threadIdx.x;
  int chunk = (N + 1023) >> 10;
  int base = t * chunk;
  int s = 0;
  for (int i = 0; i < chunk; ++i) { int idx = base + i; if (idx < N) s += cnt[idx]; }
  sums[t] = s;
  __syncthreads();
  for (int off = 1; off < 1024; off <<= 1) {
    int v = (t >= off) ? sums[t - off] : 0;
    __syncthreads();
    sums[t] += v;
    __syncthreads();
  }
  int prefix = (t > 0) ? sums[t - 1] : 0;
  for (int i = 0; i < chunk; ++i) {
    int idx = base + i;
    if (idx < N) { offs[idx] = prefix; prefix += cnt[idx]; }
  }
  if (t == 1023) offs[N] = sums[1023];
}

// scatter packed (etyp<<16)|src in CSR order — clamped at pack time
__global__ void scatter_k(const int* __restrict__ dst, const int* __restrict__ src,
                          const int* __restrict__ etyp,
                          const int* __restrict__ offs,
                          int* __restrict__ cursor, u32* __restrict__ sortedST,
                          int E, int N, int NR) {
  int e = blockIdx.x * blockDim.x + threadIdx.x;
  if (e < E) {
    int d = dst[e];
    if (d >= 0 && d < N) {
      int pos = offs[d] + atomicAdd(&cursor[d], 1);
      if (pos >= 0 && pos < E) {
        u32 s = (u32)iclamp(src[e], N);
        u32 t = (u32)iclamp(etyp[e], NR);
        sortedST[pos] = (t << 16) | s;
      }
    }
  }
}

// ================= structs =================
struct PrepArgs {
  const float* W1[3]; const float* Wmod[3]; const float* b1[3];
  const float* bmod[3]; const float* w2[3]; const float* rel;
  int K[3]; int isCopy[3];
  u16* Wc[3]; u16* PrAll; float* qr[3];
  int NR; int wcBlocks; int xK;
};
struct GArgs {
  const float* A[3]; const u16* B[3]; const float* w2[3];
  u16* PdAll; u16* PsAll; float* qd[3]; float* qs[3];
  int M; int K[3];
};
struct AgArgs {
  const u32* sortedST; const int* offs;
  const float* qd[3]; const float* qs[3]; const float* qr[3];
  const u16* PdAll; const u16* PsAll; const u16* PrAll;
  const float* alphaP; const float* gammaP;
  float* outp; int N; int NR; int E;
};

// merged weight prep: 1-D grid.  Blocks [0, wcBlocks): combined bf16 B packed
// trip-major Wc[((k>>5)*256+o)*32+(k&31)].  Blocks [wcBlocks, +3*NR): PrAll+qr.
__global__ __launch_bounds__(256) void prep_all(PrepArgs a) {
  __shared__ float red[128];
  int bid = blockIdx.x;
  int tid = threadIdx.x;
  if (bid < a.wcBlocks) {
    int m = bid / (256 * a.xK);
    int rem = bid % (256 * a.xK);
    int o = rem / a.xK;
    int kx = rem % a.xK;
    int k = kx * 256 + tid;
    int K = a.K[m];
    if (k >= K) return;
    int half = (o >= 128) ? 128 : 0;
    int oo = o & 127;
    const float* W1 = a.W1[m];
    float acc;
    if (a.isCopy[m]) {
      acc = W1[oo * 384 + half + k];
    } else {
      const float* Wm = a.Wmod[m];
      acc = 0.f;
      for (int i = 0; i < 128; ++i)
        acc += W1[oo * 384 + half + i] * Wm[i * K + k];
    }
    a.Wc[m][((size_t)(k >> 5) * 256 + o) * 32 + (k & 31)] = f2bf_rne(acc);
  } else {
    int p = bid - a.wcBlocks;
    int m = p / a.NR;
    int r = p % a.NR;
    int o = tid;
    bool act = (o < 128);
    float acc = 0.f;
    if (act) {
      const float* W1 = a.W1[m];
      acc = a.b1[m][o];
      for (int i = 0; i < 128; ++i)
        acc += W1[o * 384 + 256 + i] * a.rel[r * 128 + i];
      const float* bmod = a.bmod[m];
      if (bmod != nullptr) {
        for (int i = 0; i < 128; ++i)
          acc += (W1[o * 384 + i] + W1[o * 384 + 128 + i]) * bmod[i];
      }
      a.PrAll[(size_t)r * 384 + m * 128 + o] = f2bf_rne(acc);
      red[o] = acc * a.w2[m][o];
    }
    __syncthreads();
    for (int s = 64; s > 0; s >>= 1) {
      if (o < s) red[o] += red[o + s];
      __syncthreads();
    }
    if (o == 0) a.qr[m][r] = sane(red[0]);
  }
}

// ---------- 32-row-tile convert+GEMM, padded LDS (conflict-free) ----------
// grid (M/32, 3), 256 thr; wave wv: cols wv*64..+64 over all 32 rows (2 rg).
// A staged in 20-KB LDS chunks (8 kb-steps, row stride LROW).
// C/D layout (verified): col = lane&15, row = (lane>>4)*4 + reg
__global__ __launch_bounds__(256) void gemm_fused(GArgs g) {
  __shared__ u16 Als[8 * 32 * LROW];   // 20 KB
  __shared__ float qpart[4][32];
  int m = blockIdx.y;
  int M = g.M, K = g.K[m];
  int nt = K >> 5;                      // 4 / 16 / 24
  const u16* Bpk = g.B[m];
  const float* w2 = g.w2[m];
  int tid = threadIdx.x;
  int lane = tid & 63, wv = tid >> 6;
  int quad = lane >> 4, l16 = lane & 15;
  int row0 = blockIdx.x * 32;

  // staging map: thread → row tid>>3 (0..31), fixed kb block tid&7, 32 k each
  int srow = tid >> 3;
  int skb  = tid & 7;
  int grow = row0 + srow;
  if (grow >= M) grow = M - 1;          // dup loads; stores guarded
  const float* Ag = g.A[m] + (size_t)grow * K + skb * 32;
  u32* wbase = reinterpret_cast<u32*>(&Als[(skb * 32 + srow) * LROW]);

  const u16* Bpg = Bpk + (size_t)(wv * 64 + l16) * 32 + quad * 8;

  f32x4 acc[2][4];
  #pragma unroll
  for (int rg = 0; rg < 2; ++rg)
    #pragma unroll
    for (int t = 0; t < 4; ++t) acc[rg][t] = (f32x4){0.f, 0.f, 0.f, 0.f};

  int nchunk = (nt + 7) >> 3;
  for (int c = 0; c < nchunk; ++c) {
    int kbase = c << 8;                 // c*256
    __syncthreads();
    {
      int kg0 = kbase + skb * 32;
      if (kg0 < K) {
        #pragma unroll
        for (int i = 0; i < 8; ++i) {
          float4 v = *reinterpret_cast<const float4*>(Ag + kbase + i * 4);
          wbase[i * 2]     = packbf2(v.x, v.y);
          wbase[i * 2 + 1] = packbf2(v.z, v.w);
        }
      }
    }
    __syncthreads();
    int kbR = nt - (c << 3);
    if (kbR > 8) kbR = 8;
    for (int kbl = 0; kbl < kbR; ++kbl) {
      const u16* bp = Bpg + (size_t)((c << 3) + kbl) * 8192;
      bf16x8 b0 = *reinterpret_cast<const bf16x8*>(bp);
      bf16x8 b1 = *reinterpret_cast<const bf16x8*>(bp + 512);
      bf16x8 b2 = *reinterpret_cast<const bf16x8*>(bp + 1024);
      bf16x8 b3 = *reinterpret_cast<const bf16x8*>(bp + 1536);
      #pragma unroll
      for (int rg = 0; rg < 2; ++rg) {
        bf16x8 a = *reinterpret_cast<const bf16x8*>(
            &Als[(kbl * 32 + rg * 16 + l16) * LROW + quad * 8]);
        acc[rg][0] = __builtin_amdgcn_mfma_f32_16x16x32_bf16(a, b0, acc[rg][0], 0, 0, 0);
        acc[rg][1] = __builtin_amdgcn_mfma_f32_16x16x32_bf16(a, b1, acc[rg][1], 0, 0, 0);
        acc[rg][2] = __builtin_amdgcn_mfma_f32_16x16x32_bf16(a, b2, acc[rg][2], 0, 0, 0);
        acc[rg][3] = __builtin_amdgcn_mfma_f32_16x16x32_bf16(a, b3, acc[rg][3], 0, 0, 0);
      }
    }
  }

  // epilogue: interleaved table stores + fused q
  u16* PdAll = g.PdAll;
  u16* PsAll = g.PsAll;
  float w2c[4];
  #pragma unroll
  for (int t = 0; t < 4; ++t) w2c[t] = w2[(wv & 1) * 64 + t * 16 + l16];

  #pragma unroll
  for (int rg = 0; rg < 2; ++rg) {
    float part[4];
    #pragma unroll
    for (int r = 0; r < 4; ++r) {
      int rr = row0 + rg * 16 + quad * 4 + r;
      bool ok = rr < M;
      float qp = 0.f;
      #pragma unroll
      for (int t = 0; t < 4; ++t) {
        int cc = (wv & 1) * 64 + t * 16 + l16;
        if (ok) {
          if (wv < 2) PdAll[(size_t)rr * 384 + m * 128 + cc] = f2bf_rne(acc[rg][t][r]);
          else        PsAll[(size_t)rr * 384 + m * 128 + cc] = f2bf_rne(acc[rg][t][r]);
        }
        qp += acc[rg][t][r] * w2c[t];
      }
      #pragma unroll
      for (int mk = 1; mk < 16; mk <<= 1) qp += __shfl_xor(qp, mk, 64);
      part[r] = qp;
    }
    if (l16 == 0) {
      #pragma unroll
      for (int r = 0; r < 4; ++r) qpart[wv][rg * 16 + quad * 4 + r] = part[r];
    }
  }
  __syncthreads();
  if (tid < 64) {
    int row = tid & 31;
    int half = tid >> 5;
    int rr = row0 + row;
    if (rr < M) {
      if (half == 0) g.qd[m][rr] = sane(qpart[0][row] + qpart[1][row]);
      else           g.qs[m][rr] = sane(qpart[2][row] + qpart[3][row]);
    }
  }
}

// fused 3-modality ONLINE-softmax aggregate; packed (typ<<16|src); ×4 j-unroll
__global__ __launch_bounds__(256) void aggregate_all(AgArgs a) {
  int n = blockIdx.x * 4 + (threadIdx.x >> 6);
  if (n >= a.N) return;
  int lane = threadIdx.x & 63;
  int E = a.E;
  int eb = a.offs[n], ee = a.offs[n + 1];
  if (eb < 0) eb = 0;
  if (eb > E) eb = E;
  if (ee < eb) ee = eb;
  if (ee > E) ee = E;
  int En = ee - eb;

  float al = a.alphaP[0];
  if (!(al > 0.f && al < 1.f)) al = 0.1f;
  float ga = a.gammaP[0];
  if (!(ga > 0.f && ga < 1.f)) ga = 0.8f;
  float coef[3] = {1.f - al - ga, al, ga};

  float qdn[3];
  #pragma unroll
  for (int m = 0; m < 3; ++m) qdn[m] = sane(a.qd[m][n]);

  const u16* PsAll = a.PsAll;
  const u16* PrAll = a.PrAll;
  int dlo = 2 * lane;

  float rm[3] = {-1e30f, -1e30f, -1e30f};
  float z[3] = {0.f, 0.f, 0.f};
  float a0[3] = {0.f, 0.f, 0.f};
  float a1[3] = {0.f, 0.f, 0.f};
  for (int c0 = 0; c0 < En; c0 += 64) {
    int cn = min(64, En - c0);
    u32 stp = 0;
    float bm[3] = {-1e30f, -1e30f, -1e30f};
    if (lane < cn) {
      stp = a.sortedST[eb + c0 + lane];
      int s = (int)(stp & 0xffffu);
      int t = (int)(stp >> 16);
      #pragma unroll
      for (int m = 0; m < 3; ++m)
        bm[m] = lrelu(qdn[m] + a.qs[m][s] + a.qr[m][t]);
    }
    float wr[3];
    #pragma unroll
    for (int m = 0; m < 3; ++m) {
      float cm = wred_max(bm[m]);
      float nm = fmaxf(rm[m], cm);
      float sc = __expf(fmaxf(rm[m] - nm, -80.f));
      z[m] *= sc; a0[m] *= sc; a1[m] *= sc;
      rm[m] = nm;
      wr[m] = (lane < cn) ? __expf(fmaxf(bm[m] - nm, -80.f)) : 0.f;
      z[m] += wr[m];
    }

    int cnR = (cn + 3) & ~3;
    for (int j = 0; j < cnR; j += 4) {
      u32 stj[4];
      float wj[4][3];
      #pragma unroll
      for (int u = 0; u < 4; ++u) {
        stj[u] = __shfl(stp, j + u, 64);
        wj[u][0] = __shfl(wr[0], j + u, 64);
        wj[u][1] = __shfl(wr[1], j + u, 64);
        wj[u][2] = __shfl(wr[2], j + u, 64);
      }
      u32 pu[4][3], ru[4][3];
      #pragma unroll
      for (int u = 0; u < 4; ++u) {
        const u16* ps = PsAll + (size_t)(stj[u] & 0xffffu) * 384 + dlo;
        const u16* pr = PrAll + (size_t)(stj[u] >> 16) * 384 + dlo;
        #pragma unroll
        for (int m = 0; m < 3; ++m) {
          pu[u][m] = *reinterpret_cast<const u32*>(ps + m * 128);
          ru[u][m] = *reinterpret_cast<const u32*>(pr + m * 128);
        }
      }
      #pragma unroll
      for (int u = 0; u < 4; ++u) {
        #pragma unroll
        for (int m = 0; m < 3; ++m) {
          float ps0 = __uint_as_float(pu[u][m] << 16);
          float ps1 = __uint_as_float(pu[u][m] & 0xffff0000u);
          float pr0 = __uint_as_float(ru[u][m] << 16);
          float pr1 = __uint_as_float(ru[u][m] & 0xffff0000u);
          a0[m] = fmaf(wj[u][m], ps0 + pr0, a0[m]);
          a1[m] = fmaf(wj[u][m], ps1 + pr1, a1[m]);
        }
      }
    }
  }
  #pragma unroll
  for (int m = 0; m < 3; ++m) z[m] = wred_sum(z[m]);

  float o0 = 0.f, o1 = 0.f;
  const u16* pd = a.PdAll + (size_t)n * 384 + dlo;
  #pragma unroll
  for (int m = 0; m < 3; ++m) {
    float h0 = 0.f, h1 = 0.f;
    if (En > 0 && z[m] > 0.f) {
      float rz = 1.f / z[m];
      u32 du = *reinterpret_cast<const u32*>(pd + m * 128);
      float pd0 = __uint_as_float(du << 16), pd1 = __uint_as_float(du & 0xffff0000u);
      h0 = lrelu(pd0 + a0[m] * rz);
      h1 = lrelu(pd1 + a1[m] * rz);
    }
    o0 = fmaf(coef[m], h0, o0);
    o1 = fmaf(coef[m], h1, o1);
  }
  float* op = a.outp + (size_t)n * 128 + dlo;
  op[0] = sane(o0);
  op[1] = sane(o1);
}

extern "C" void kernel_launch(void* const* d_in, const int* in_sizes, int n_in,
                              void* d_out, int out_size, void* d_ws, size_t ws_size,
                              hipStream_t stream) {
  const int* ei        = (const int*)d_in[1];
  const int* et        = (const int*)d_in[2];
  const float* visual  = (const float*)d_in[3];
  const float* textual = (const float*)d_in[4];
  const float* semb    = (const float*)d_in[5];
  const float* relemb  = (const float*)d_in[6];
  const float* W1s = (const float*)d_in[7];
  const float* b1s = (const float*)d_in[8];
  const float* w2s = (const float*)d_in[9];
  const float* W1v = (const float*)d_in[10];
  const float* b1v = (const float*)d_in[11];
  const float* w2v = (const float*)d_in[12];
  const float* W1t = (const float*)d_in[13];
  const float* b1t = (const float*)d_in[14];
  const float* w2t = (const float*)d_in[15];
  const float* Wv  = (const float*)d_in[16];
  const float* bv  = (const float*)d_in[17];
  const float* Wt  = (const float*)d_in[18];
  const float* bt  = (const float*)d_in[19];
  const float* alphaP = (const float*)d_in[20];
  const float* gammaP = (const float*)d_in[21];
  float* outp = (float*)d_out;

  const int E   = in_sizes[2];
  const int N   = in_sizes[5] / DIM;
  const int NR  = in_sizes[6] / DIM;
  const int VIS = in_sizes[3] / N;   // 512
  const int TXT = in_sizes[4] / N;   // 768
  const int KMAX = (TXT > VIS) ? TXT : VIS;
  int Ks[3] = {DIM, VIS, TXT};
  const int NT32 = (N + 31) / 32;

  const float* W1a[3]   = {W1s, W1v, W1t};
  const float* b1a[3]   = {b1s, b1v, b1t};
  const float* w2a[3]   = {w2s, w2v, w2t};
  const float* Wmoda[3] = {nullptr, Wv, Wt};
  const float* bmoda[3] = {nullptr, bv, bt};
  const float* Amoda[3] = {semb, visual, textual};

  const int* esrc = ei;
  const int* edst = ei + E;
  int egrid = (E + 255) / 256;

  size_t off = 0;
  auto take = [&](size_t bytes) -> size_t {
    size_t o = off;
    off = (off + bytes + 255) & ~(size_t)255;
    return o;
  };
  size_t o_cnt  = take((size_t)2 * N * 4);
  size_t o_offs = take((size_t)(N + 1) * 4);
  size_t o_st   = take((size_t)E * 4);
  size_t meta_end = off;
  size_t o_qdm[3], o_qsm[3], o_qrm[3], o_Wcm[3];
  for (int m = 0; m < 3; ++m) {
    o_qdm[m] = take((size_t)N * 4);
    o_qsm[m] = take((size_t)N * 4);
    o_qrm[m] = take((size_t)NR * 4);
    o_Wcm[m] = take((size_t)256 * Ks[m] * 2);
  }
  size_t o_PrAll = take((size_t)NR * 384 * 2);
  size_t o_PdAll = take((size_t)N * 384 * 2);
  size_t o_PsAll = take((size_t)N * 384 * 2);
  size_t need = off;                           // ~17.5 MB

  if (ws_size < need) {
    hipMemsetAsync(d_out, 0, (size_t)out_size * 4, stream);  // finite diagnostic
    return;
  }

  char* w = (char*)d_ws;
  int* counts = (int*)(w + o_cnt);
  int* cursor = counts + N;
  int* offs   = (int*)(w + o_offs);
  u32* sortedST = (u32*)(w + o_st);

  hipMemsetAsync(w, 0, meta_end, stream);
  hist_k<<<egrid, 256, 0, stream>>>(edst, counts, E, N);
  scan_k<<<1, 1024, 0, stream>>>(counts, offs, N);
  scatter_k<<<egrid, 256, 0, stream>>>(edst, esrc, et, offs, cursor, sortedST, E, N, NR);

  PrepArgs pa;
  GArgs ga;
  AgArgs aa;
  pa.rel = relemb; pa.NR = NR;
  pa.xK = (KMAX + 255) / 256;
  pa.wcBlocks = 3 * 256 * pa.xK;
  pa.PrAll = (u16*)(w + o_PrAll);
  ga.M = N;
  ga.PdAll = (u16*)(w + o_PdAll);
  ga.PsAll = (u16*)(w + o_PsAll);
  for (int m = 0; m < 3; ++m) {
    pa.W1[m] = W1a[m]; pa.Wmod[m] = Wmoda[m]; pa.b1[m] = b1a[m];
    pa.bmod[m] = bmoda[m]; pa.w2[m] = w2a[m];
    pa.K[m] = Ks[m];
    pa.isCopy[m] = (m == 0);
    pa.Wc[m] = (u16*)(w + o_Wcm[m]);
    pa.qr[m] = (float*)(w + o_qrm[m]);
    ga.A[m] = Amoda[m]; ga.B[m] = (const u16*)(w + o_Wcm[m]); ga.w2[m] = w2a[m];
    ga.qd[m] = (float*)(w + o_qdm[m]); ga.qs[m] = (float*)(w + o_qsm[m]);
    ga.K[m] = Ks[m];
    aa.qd[m] = (const float*)(w + o_qdm[m]);
    aa.qs[m] = (const float*)(w + o_qsm[m]);
    aa.qr[m] = (const float*)(w + o_qrm[m]);
  }
  aa.PdAll = (const u16*)(w + o_PdAll);
  aa.PsAll = (const u16*)(w + o_PsAll);
  aa.PrAll = (const u16*)(w + o_PrAll);
  aa.sortedST = sortedST; aa.offs = offs;
  aa.alphaP = alphaP; aa.gammaP = gammaP;
  aa.outp = outp; aa.N = N; aa.NR = NR; aa.E = E;

  prep_all<<<pa.wcBlocks + 3 * NR, 256, 0, stream>>>(pa);
  gemm_fused<<<dim3(NT32, 3), 256, 0, stream>>>(ga);
  aggregate_all<<<(N + 3) / 4, 256, 0, stream>>>(aa);
}